// Round 1
// baseline (7255.786 us; speedup 1.0000x reference)
//
#include <hip/hip_runtime.h>
#include <hip/hip_bf16.h>
#include <stdint.h>

#define NB 64
#define NS 1024
#define ND 1024
#define NG 4096
#define CHUNK 256
#define NCHUNK 4

typedef __attribute__((ext_vector_type(4))) float f32x4;
typedef __attribute__((ext_vector_type(8))) short bf16x8;
typedef __attribute__((ext_vector_type(4))) int i32x4;

__device__ __forceinline__ float bf2f(uint16_t u) {
  return __uint_as_float(((uint32_t)u) << 16);
}
__device__ __forceinline__ uint16_t f2bf(float f) {
  uint32_t x = __float_as_uint(f);
  uint32_t r = (x + 0x7fffu + ((x >> 16) & 1u)) >> 16;
  return (uint16_t)r;
}
__device__ __forceinline__ float sigmoidf_(float x) {
  x = fminf(fmaxf(x, -30.f), 30.f);
  return 1.f / (1.f + __expf(-x));
}
__device__ __forceinline__ float tanhf_(float x) {
  x = fminf(fmaxf(x, -15.f), 15.f);
  float e = __expf(2.f * x);
  return (e - 1.f) / (e + 1.f);
}

__device__ __forceinline__ void gload_lds16(const void* g, void* l) {
  __builtin_amdgcn_global_load_lds(
      (const __attribute__((address_space(1))) uint32_t*)g,
      (__attribute__((address_space(3))) uint32_t*)l, 16, 0, 0);
}

// ---------------- convert fp32 -> bf16 (vectorized) ----------------
__global__ void k_cvt(const float* __restrict__ src, uint16_t* __restrict__ dst, int n4) {
  int stride = gridDim.x * blockDim.x;
  for (int i = blockIdx.x * blockDim.x + threadIdx.x; i < n4; i += stride) {
    float4 v = ((const float4*)src)[i];
    ushort4 o;
    o.x = f2bf(v.x); o.y = f2bf(v.y); o.z = f2bf(v.z); o.w = f2bf(v.w);
    ((ushort4*)dst)[i] = o;
  }
}

// ---------------- phase 1: x_proj chunk GEMM ----------------
// XP[s_loc*64 + b][n] = sum_k emb_bf[b*NS + t0 + s_loc][k] * Wx[n][k]
__global__ __launch_bounds__(256) void k_gemm(const uint16_t* __restrict__ Abase,
                                              const uint16_t* __restrict__ Wx,
                                              uint16_t* __restrict__ XP, int t0) {
  __shared__ uint16_t lA[128 * 32];
  __shared__ uint16_t lB[128 * 32];
  const int tid = threadIdx.x;
  const int mb = blockIdx.x, nb = blockIdx.y;
  const int b = mb >> 1;
  const int s_base = t0 + ((mb & 1) << 7);
  const uint16_t* A0 = Abase + ((size_t)b * NS + s_base) * ND;
  const uint16_t* B0 = Wx + (size_t)(nb * 128) * ND;
  const int lane = tid & 63, wv = tid >> 6;
  const int m_off = (wv >> 1) << 6, n_off = (wv & 1) << 6;

  f32x4 acc[4][4] = {};
  for (int kb = 0; kb < ND / 32; ++kb) {
    const int k0 = kb * 32;
#pragma unroll
    for (int j = 0; j < 2; ++j) {
      int cid = j * 256 + tid;          // 0..511 16B chunks
      int row = cid >> 2, cc = cid & 3;
      int cs = cc ^ (row & 3);          // source pre-swizzle
      gload_lds16(A0 + (size_t)row * ND + k0 + cs * 8, (char*)lA + cid * 16);
      gload_lds16(B0 + (size_t)row * ND + k0 + cs * 8, (char*)lB + cid * 16);
    }
    __syncthreads();
    bf16x8 af[4], bfr[4];
#pragma unroll
    for (int i = 0; i < 4; ++i) {
      int row = m_off + i * 16 + (lane & 15);
      int ch = (lane >> 4) ^ (row & 3);
      af[i] = *(const bf16x8*)((const char*)lA + row * 64 + ch * 16);
      int rowb = n_off + i * 16 + (lane & 15);
      int chb = (lane >> 4) ^ (rowb & 3);
      bfr[i] = *(const bf16x8*)((const char*)lB + rowb * 64 + chb * 16);
    }
#pragma unroll
    for (int i = 0; i < 4; ++i)
#pragma unroll
      for (int j2 = 0; j2 < 4; ++j2)
        acc[i][j2] = __builtin_amdgcn_mfma_f32_16x16x32_bf16(af[i], bfr[j2], acc[i][j2], 0, 0, 0);
    __syncthreads();
  }
  const int s_loc0 = ((mb & 1) << 7);
#pragma unroll
  for (int i = 0; i < 4; ++i)
#pragma unroll
    for (int j2 = 0; j2 < 4; ++j2)
#pragma unroll
      for (int r = 0; r < 4; ++r) {
        int m = m_off + i * 16 + ((lane >> 4) << 2) + r;
        int n = nb * 128 + n_off + j2 * 16 + (lane & 15);
        int s_loc = s_loc0 + m;
        XP[((size_t)(s_loc * NB + b)) * NG + n] = f2bf(acc[i][j2][r]);
      }
}

// ---------------- phase 2: persistent LSTM chunk ----------------
// 256 WGs: (g_b in 0..3) x (g_d in 0..63). WG owns batches [g_b*16,+16), d [g_d*16,+16).
__global__ __launch_bounds__(256) void k_lstm(
    const uint16_t* __restrict__ Wh, const uint16_t* __restrict__ XP,
    const float* __restrict__ b_i, const float* __restrict__ b_f,
    const float* __restrict__ b_g, const float* __restrict__ b_o,
    uint16_t* __restrict__ hbuf, float* __restrict__ cbuf,
    uint32_t* __restrict__ flags, float* __restrict__ out, int t0) {
  extern __shared__ char smem[];
  uint16_t* lW = (uint16_t*)smem;                                  // 131072 B
  uint16_t* lH = (uint16_t*)(smem + 131072);                       // 16384 B
  float* lG = (float*)(smem + 131072 + 16384);                     // 4096 B
  uint16_t* lHO = (uint16_t*)(smem + 131072 + 16384 + 4096);       // 512 B

  const int tid = threadIdx.x;
  const int lane = tid & 63, wv = tid >> 6;
  const int bid = blockIdx.x;
  const int xcd = bid & 7;
  const int g_b = xcd >> 1;
  const int g_d = (xcd & 1) + ((bid >> 3) << 1);

  // load this WG's 64 Wh rows into LDS (swizzled: 16B-chunk ^= (row&7))
  for (int it = tid; it < 64 * 128; it += 256) {
    int r = it >> 7;
    int ch = it & 127;
    int gr = ((r >> 4) * ND) + (g_d * 16) + (r & 15);
    const uint16_t* src = Wh + (size_t)gr * ND + ch * 8;
    i32x4 v = *(const i32x4*)src;
    int chs = ch ^ (r & 7);
    *(i32x4*)((char*)lW + r * 2048 + chs * 16) = v;
  }

  const int bl = tid >> 4, dloc = tid & 15;
  const int bg = g_b * 16 + bl, dg = g_d * 16 + dloc;
  float Bi = b_i[dg], Bf = b_f[dg], Bg = b_g[dg], Bo = b_o[dg];
  float c = (t0 == 0) ? 0.f : cbuf[bg * ND + dg];
  __syncthreads();

  for (int t = t0; t < t0 + CHUNK; ++t) {
    f32x4 acc0 = {}, acc1 = {}, acc2 = {}, acc3 = {};
    if (t > 0) {
      const int par = (t - 1) & 1;
      if (wv == 0) {
        const uint32_t* fl = &flags[((size_t)g_b * NS + (t - 1)) * 64 + lane];
        uint32_t v;
        do {
          v = __hip_atomic_load((uint32_t*)fl, __ATOMIC_RELAXED, __HIP_MEMORY_SCOPE_AGENT);
        } while (__any(v == 0));
      }
      __syncthreads();
      const uint16_t* hsrc = hbuf + ((size_t)par * NB + g_b * 16) * ND;
#pragma unroll 1
      for (int half = 0; half < 2; ++half) {
        {
          int r = tid >> 4, seg = tid & 15;
          const uint16_t* s = hsrc + (size_t)r * ND + half * 512 + seg * 32;
#pragma unroll
          for (int cq = 0; cq < 4; ++cq) {
            uint64_t lo = __hip_atomic_load((uint64_t*)(s + cq * 8), __ATOMIC_RELAXED, __HIP_MEMORY_SCOPE_AGENT);
            uint64_t hi = __hip_atomic_load((uint64_t*)(s + cq * 8 + 4), __ATOMIC_RELAXED, __HIP_MEMORY_SCOPE_AGENT);
            int ch = seg * 4 + cq;
            int chs = ch ^ (r & 7);
            uint64_t* d = (uint64_t*)((char*)lH + r * 1024 + chs * 16);
            d[0] = lo; d[1] = hi;
          }
        }
        __syncthreads();
#pragma unroll
        for (int kk = 0; kk < 16; ++kk) {
          int ra = lane & 15;
          int cha = (kk * 4 + (lane >> 4)) ^ (ra & 7);
          bf16x8 a = *(const bf16x8*)((const char*)lH + ra * 1024 + cha * 16);
          int rb = wv * 16 + (lane & 15);
          int chb = ((half * 16 + kk) * 4 + (lane >> 4)) ^ (rb & 7);
          bf16x8 w8 = *(const bf16x8*)((const char*)lW + rb * 2048 + chb * 16);
          if ((kk & 3) == 0)      acc0 = __builtin_amdgcn_mfma_f32_16x16x32_bf16(a, w8, acc0, 0, 0, 0);
          else if ((kk & 3) == 1) acc1 = __builtin_amdgcn_mfma_f32_16x16x32_bf16(a, w8, acc1, 0, 0, 0);
          else if ((kk & 3) == 2) acc2 = __builtin_amdgcn_mfma_f32_16x16x32_bf16(a, w8, acc2, 0, 0, 0);
          else                    acc3 = __builtin_amdgcn_mfma_f32_16x16x32_bf16(a, w8, acc3, 0, 0, 0);
        }
        __syncthreads();
      }
    }
    // gates to LDS: wave wv owns gate type wv; D: col=lane&15 (d), row=(lane>>4)*4+r (batch)
#pragma unroll
    for (int r = 0; r < 4; ++r) {
      float gsum = acc0[r] + acc1[r] + acc2[r] + acc3[r];
      lG[wv * 256 + ((lane >> 4) * 4 + r) * 16 + (lane & 15)] = gsum;
    }
    __syncthreads();

    size_t xpb = (((size_t)(t - t0) * NB) + bg) * NG + dg;
    float xi = bf2f(XP[xpb])        + lG[0 * 256 + bl * 16 + dloc] + Bi;
    float xf = bf2f(XP[xpb + 1024]) + lG[1 * 256 + bl * 16 + dloc] + Bf;
    float xg = bf2f(XP[xpb + 2048]) + lG[2 * 256 + bl * 16 + dloc] + Bg;
    float xo = bf2f(XP[xpb + 3072]) + lG[3 * 256 + bl * 16 + dloc] + Bo;
    float ig = sigmoidf_(xi), fg = sigmoidf_(xf), gg = tanhf_(xg), og = sigmoidf_(xo);
    c = fg * c + ig * gg;
    float h = og * tanhf_(c);
    lHO[bl * 16 + dloc] = f2bf(h);
    if (t == NS - 1) out[bg * ND + dg] = h;
    __syncthreads();

    if (tid < 128) {
      uint32_t pair = *(const uint32_t*)&lHO[tid * 2];
      int r = tid >> 3, cc = tid & 7;
      uint16_t* dst = hbuf + ((size_t)(t & 1) * NB + g_b * 16 + r) * ND + g_d * 16 + cc * 2;
      __hip_atomic_store((uint32_t*)dst, pair, __ATOMIC_RELAXED, __HIP_MEMORY_SCOPE_AGENT);
    }
    __syncthreads();  // drains vmcnt in every wave -> h stores are in L3
    if (tid == 0)
      __hip_atomic_store(&flags[((size_t)g_b * NS + t) * 64 + g_d], 1u,
                         __ATOMIC_RELAXED, __HIP_MEMORY_SCOPE_AGENT);
  }
  cbuf[bg * ND + dg] = c;
}

// ---------------- launch ----------------
extern "C" void kernel_launch(void* const* d_in, const int* in_sizes, int n_in,
                              void* d_out, int out_size, void* d_ws, size_t ws_size,
                              hipStream_t stream) {
  const float* emb = (const float*)d_in[0];
  const float* W_ii = (const float*)d_in[1];
  const float* b_ii = (const float*)d_in[2];
  const float* W_if = (const float*)d_in[3];
  const float* b_if = (const float*)d_in[4];
  const float* W_ig = (const float*)d_in[5];
  const float* b_ig = (const float*)d_in[6];
  const float* W_io = (const float*)d_in[7];
  const float* b_io = (const float*)d_in[8];
  const float* W_hi = (const float*)d_in[9];
  const float* W_hf = (const float*)d_in[10];
  const float* W_hg = (const float*)d_in[11];
  const float* W_ho = (const float*)d_in[12];

  char* ws = (char*)d_ws;
  uint16_t* embb  = (uint16_t*)ws;                       // 134217728 B
  uint16_t* wx    = (uint16_t*)(ws + 134217728);         // 8388608 B
  uint16_t* wh    = (uint16_t*)(ws + 142606336);         // 8388608 B
  uint16_t* xp    = (uint16_t*)(ws + 150994944);         // 134217728 B
  uint16_t* hbuf  = (uint16_t*)(ws + 285212672);         // 262144 B
  float*    cbuf  = (float*)(ws + 285474816);            // 262144 B
  uint32_t* flags = (uint32_t*)(ws + 285736960);         // 1048576 B

  hipMemsetAsync(flags, 0, (size_t)4 * 1024 * 64 * 4, stream);

  k_cvt<<<2048, 256, 0, stream>>>(emb, embb, 64 * 1024 * 1024 / 4);
  k_cvt<<<256, 256, 0, stream>>>(W_ii, wx + 0 * 1048576, 262144);
  k_cvt<<<256, 256, 0, stream>>>(W_if, wx + 1 * 1048576, 262144);
  k_cvt<<<256, 256, 0, stream>>>(W_ig, wx + 2 * 1048576, 262144);
  k_cvt<<<256, 256, 0, stream>>>(W_io, wx + 3 * 1048576, 262144);
  k_cvt<<<256, 256, 0, stream>>>(W_hi, wh + 0 * 1048576, 262144);
  k_cvt<<<256, 256, 0, stream>>>(W_hf, wh + 1 * 1048576, 262144);
  k_cvt<<<256, 256, 0, stream>>>(W_hg, wh + 2 * 1048576, 262144);
  k_cvt<<<256, 256, 0, stream>>>(W_ho, wh + 3 * 1048576, 262144);

  const int LSTM_SHM = 131072 + 16384 + 4096 + 512;  // 152064 B
  hipFuncSetAttribute((const void*)k_lstm, hipFuncAttributeMaxDynamicSharedMemorySize, LSTM_SHM);

  for (int chk = 0; chk < NCHUNK; ++chk) {
    k_gemm<<<dim3(128, 32), 256, 0, stream>>>(embb, wx, xp, chk * CHUNK);
    k_lstm<<<256, 256, LSTM_SHM, stream>>>(wh, xp, b_ii, b_if, b_ig, b_io,
                                           hbuf, cbuf, flags, (float*)d_out, chk * CHUNK);
  }
}

// Round 2
// 5242.194 us; speedup vs baseline: 1.3841x; 1.3841x over previous
//
#include <hip/hip_runtime.h>
#include <stdint.h>

#define NB 64
#define NS 1024
#define ND 1024
#define NG 4096
#define CHUNK 256
#define NCHUNK 4

typedef __attribute__((ext_vector_type(4))) float f32x4;
typedef __attribute__((ext_vector_type(8))) short bf16x8;

__device__ __forceinline__ float bf2f(uint16_t u) {
  return __uint_as_float(((uint32_t)u) << 16);
}
__device__ __forceinline__ uint16_t f2bf(float f) {
  uint32_t x = __float_as_uint(f);
  return (uint16_t)((x + 0x7fffu + ((x >> 16) & 1u)) >> 16);
}
__device__ __forceinline__ float sigmoidf_(float x) {
  x = fminf(fmaxf(x, -30.f), 30.f);
  return 1.f / (1.f + __expf(-x));
}
__device__ __forceinline__ float tanhf_(float x) {
  x = fminf(fmaxf(x, -15.f), 15.f);
  float e = __expf(2.f * x);
  return (e - 1.f) / (e + 1.f);
}
__device__ __forceinline__ void gload_lds16(const void* g, void* l) {
  __builtin_amdgcn_global_load_lds(
      (const __attribute__((address_space(1))) uint32_t*)g,
      (__attribute__((address_space(3))) uint32_t*)l, 16, 0, 0);
}

// ---------------- convert fp32 -> bf16 (vectorized) ----------------
__global__ void k_cvt(const float* __restrict__ src, uint16_t* __restrict__ dst, int n4) {
  int stride = gridDim.x * blockDim.x;
  for (int i = blockIdx.x * blockDim.x + threadIdx.x; i < n4; i += stride) {
    float4 v = ((const float4*)src)[i];
    ushort4 o;
    o.x = f2bf(v.x); o.y = f2bf(v.y); o.z = f2bf(v.z); o.w = f2bf(v.w);
    ((ushort4*)dst)[i] = o;
  }
}

// ---------------- phase 1: x_proj chunk GEMM (m97-style, unchanged) ----------------
__global__ __launch_bounds__(256) void k_gemm(const uint16_t* __restrict__ Abase,
                                              const uint16_t* __restrict__ Wx,
                                              uint16_t* __restrict__ XP, int t0) {
  __shared__ uint16_t lA[128 * 32];
  __shared__ uint16_t lB[128 * 32];
  const int tid = threadIdx.x;
  const int mb = blockIdx.x, nb = blockIdx.y;
  const int b = mb >> 1;
  const int s_base = t0 + ((mb & 1) << 7);
  const uint16_t* A0 = Abase + ((size_t)b * NS + s_base) * ND;
  const uint16_t* B0 = Wx + (size_t)(nb * 128) * ND;
  const int lane = tid & 63, wv = tid >> 6;
  const int m_off = (wv >> 1) << 6, n_off = (wv & 1) << 6;

  f32x4 acc[4][4] = {};
  for (int kb = 0; kb < ND / 32; ++kb) {
    const int k0 = kb * 32;
#pragma unroll
    for (int j = 0; j < 2; ++j) {
      int cid = j * 256 + tid;
      int row = cid >> 2, cc = cid & 3;
      int cs = cc ^ (row & 3);
      gload_lds16(A0 + (size_t)row * ND + k0 + cs * 8, (char*)lA + cid * 16);
      gload_lds16(B0 + (size_t)row * ND + k0 + cs * 8, (char*)lB + cid * 16);
    }
    __syncthreads();
    bf16x8 af[4], bfr[4];
#pragma unroll
    for (int i = 0; i < 4; ++i) {
      int row = m_off + i * 16 + (lane & 15);
      int ch = (lane >> 4) ^ (row & 3);
      af[i] = *(const bf16x8*)((const char*)lA + row * 64 + ch * 16);
      int rowb = n_off + i * 16 + (lane & 15);
      int chb = (lane >> 4) ^ (rowb & 3);
      bfr[i] = *(const bf16x8*)((const char*)lB + rowb * 64 + chb * 16);
    }
#pragma unroll
    for (int i = 0; i < 4; ++i)
#pragma unroll
      for (int j2 = 0; j2 < 4; ++j2)
        acc[i][j2] = __builtin_amdgcn_mfma_f32_16x16x32_bf16(af[i], bfr[j2], acc[i][j2], 0, 0, 0);
    __syncthreads();
  }
  const int s_loc0 = ((mb & 1) << 7);
#pragma unroll
  for (int i = 0; i < 4; ++i)
#pragma unroll
    for (int j2 = 0; j2 < 4; ++j2)
#pragma unroll
      for (int r = 0; r < 4; ++r) {
        int m = m_off + i * 16 + ((lane >> 4) << 2) + r;
        int n = nb * 128 + n_off + j2 * 16 + (lane & 15);
        int s_loc = s_loc0 + m;
        XP[((size_t)(s_loc * NB + b)) * NG + n] = f2bf(acc[i][j2][r]);
      }
}

// ---------------- phase 2: persistent LSTM chunk ----------------
// 256 WGs: (g_b 0..3) x (g_d 0..63). WG owns batches [g_b*16,+16), d [g_d*16,+16).
// Wh fragments live in registers (128 VGPR); h staged via global_load_lds into
// 32 KB LDS, swizzle pre-applied at the producer's store address.
// h(t, batch b) is stored aliased onto embb[b][s=t] (already consumed by gemm)
// so every h address is read exactly once per dispatch -> no stale-cache hazard.
__global__ __launch_bounds__(256) void k_lstm(
    const uint16_t* __restrict__ Wh,     // [4*1024][1024] bf16
    const uint16_t* __restrict__ XP,     // [CHUNK*64][4096] bf16 (chunk-local)
    const float* __restrict__ b_i, const float* __restrict__ b_f,
    const float* __restrict__ b_g, const float* __restrict__ b_o,
    uint16_t* __restrict__ hring,        // == embb; h(t,b) row at (b*NS + t)*ND
    float* __restrict__ cbuf,
    uint32_t* __restrict__ flags,        // [4][NS][64]
    float* __restrict__ out, int t0) {
  __shared__ uint16_t lH[16 * 1024];     // 32 KB: 16 batch rows x 2048 B (swizzled chunks)

  const int tid = threadIdx.x;
  const int lane = tid & 63, wv = tid >> 6;
  const int bid = blockIdx.x;
  const int xcd = bid & 7;
  const int g_b = xcd >> 1;
  const int g_d = (xcd & 1) + ((bid >> 3) << 1);

  const int q = lane >> 4, nl = lane & 15;
  const int d_loc = wv * 4 + (nl >> 2);        // 0..15 within WG
  const int g = nl & 3;                        // gate id (0=i,1=f,2=g,3=o)
  const int dg = g_d * 16 + d_loc;             // global d 0..1023
  const int bg0 = g_b * 16 + q * 4;            // batch base for r=0..3

  // ---- Wh fragments into registers: lane's output col = (gate g, row dg) ----
  const uint16_t* wrow = Wh + ((size_t)g * ND + dg) * ND;
  bf16x8 wfr[32];
#pragma unroll
  for (int kk = 0; kk < 32; ++kk)
    wfr[kk] = *(const bf16x8*)(wrow + kk * 32 + q * 8);

  const float* bptr = (g == 0) ? b_i : (g == 1) ? b_f : (g == 2) ? b_g : b_o;
  const float Bv = bptr[dg];

  float c0, c1, c2, c3;
  if (t0 == 0) {
    c0 = c1 = c2 = c3 = 0.f;
  } else {
    c0 = cbuf[(size_t)(bg0 + 0) * ND + dg];
    c1 = cbuf[(size_t)(bg0 + 1) * ND + dg];
    c2 = cbuf[(size_t)(bg0 + 2) * ND + dg];
    c3 = cbuf[(size_t)(bg0 + 3) * ND + dg];
  }

  for (int t = t0; t < t0 + CHUNK; ++t) {
    // XP prefetch (independent of h -> issued before the flag wait)
    const uint16_t* xpb = XP + (((size_t)(t - t0) * NB) + bg0) * NG + ((size_t)g << 10) + dg;
    uint16_t x0 = xpb[0], x1 = xpb[NG], x2 = xpb[2 * (size_t)NG], x3 = xpb[3 * (size_t)NG];

    f32x4 a0 = {0,0,0,0}, a1 = {0,0,0,0}, a2 = {0,0,0,0}, a3 = {0,0,0,0};
    if (t > 0) {
      // all 4 waves poll the 64 producer flags of our batch group
      const uint32_t* fl = flags + (((size_t)g_b * NS) + (t - 1)) * 64 + lane;
      uint32_t v;
      do {
        v = __hip_atomic_load(fl, __ATOMIC_RELAXED, __HIP_MEMORY_SCOPE_AGENT);
      } while (__any(v == 0));
      // stage h(t-1): 16 rows x 2048 B, 32 x 1KB global_load_lds (8 per wave)
#pragma unroll
      for (int j = 0; j < 8; ++j) {
        int inst = wv * 8 + j;                 // 0..31
        int row = inst >> 1;                   // batch row 0..15
        const uint16_t* src = hring + (((size_t)(g_b * 16 + row) * NS) + (t - 1)) * ND
                              + (inst & 1) * 512;
        gload_lds16((const char*)src + lane * 16, (char*)lH + inst * 1024 + lane * 16);
      }
      __syncthreads();   // drains global_load_lds; lH ready
      // MFMA: acc += h(t-1) @ Wh^T for this lane's column; 4 chains for ILP
#pragma unroll
      for (int kk = 0; kk < 32; ++kk) {
        int cs = (kk * 4 + q) ^ (nl & 7);
        bf16x8 af = *(const bf16x8*)((const char*)lH + nl * 2048 + cs * 16);
        if ((kk & 3) == 0)      a0 = __builtin_amdgcn_mfma_f32_16x16x32_bf16(af, wfr[kk], a0, 0, 0, 0);
        else if ((kk & 3) == 1) a1 = __builtin_amdgcn_mfma_f32_16x16x32_bf16(af, wfr[kk], a1, 0, 0, 0);
        else if ((kk & 3) == 2) a2 = __builtin_amdgcn_mfma_f32_16x16x32_bf16(af, wfr[kk], a2, 0, 0, 0);
        else                    a3 = __builtin_amdgcn_mfma_f32_16x16x32_bf16(af, wfr[kk], a3, 0, 0, 0);
      }
    }

    float xr0 = bf2f(x0), xr1 = bf2f(x1), xr2 = bf2f(x2), xr3 = bf2f(x3);
    float cc[4] = { c0, c1, c2, c3 };
    float xr[4] = { xr0, xr1, xr2, xr3 };
    float hval = 0.f;
#pragma unroll
    for (int r = 0; r < 4; ++r) {
      float v = a0[r] + a1[r] + a2[r] + a3[r] + xr[r] + Bv;
      // allgather the 4 gate values across the 4-lane (gate) group
      float s1 = __shfl_xor(v, 1);
      float pe = (g & 1) ? s1 : v;
      float po = (g & 1) ? v : s1;
      float qe = __shfl_xor(pe, 2);
      float qo = __shfl_xor(po, 2);
      float gi = (g & 2) ? qe : pe;
      float gf = (g & 2) ? qo : po;
      float gg = (g & 2) ? pe : qe;
      float go = (g & 2) ? po : qo;
      float it = sigmoidf_(gi), ft = sigmoidf_(gf), gt = tanhf_(gg), ot = sigmoidf_(go);
      float cn = ft * cc[r] + it * gt;
      cc[r] = cn;
      float h = ot * tanhf_(cn);
      if (r == g) hval = h;   // lane stores batch bg0+g
    }
    c0 = cc[0]; c1 = cc[1]; c2 = cc[2]; c3 = cc[3];

    {
      const int bsel = bg0 + g;          // global batch this lane stores
      const int bl = q * 4 + g;          // local batch row (consumer LDS row)
      uint16_t hb = f2bf(hval);
      int cs2 = (dg >> 3) ^ (bl & 7);    // producer-side swizzle (chunk ^ row)
      uint16_t* dst = hring + (((size_t)bsel * NS) + t) * ND + cs2 * 8 + (dg & 7);
      __hip_atomic_store(dst, hb, __ATOMIC_RELAXED, __HIP_MEMORY_SCOPE_AGENT);
      if (t == NS - 1) out[(size_t)bsel * ND + dg] = hval;
    }
    __syncthreads();   // drains h stores (vmcnt) in all waves; also guards lH reuse
    if (tid == 0)
      __hip_atomic_store(flags + (((size_t)g_b * NS) + t) * 64 + g_d, 1u,
                         __ATOMIC_RELAXED, __HIP_MEMORY_SCOPE_AGENT);
  }

  // save c-state for the next chunk (lane stores its r=g element)
  float cstore = (g == 0) ? c0 : (g == 1) ? c1 : (g == 2) ? c2 : c3;
  cbuf[(size_t)(bg0 + g) * ND + dg] = cstore;
}

// ---------------- launch ----------------
extern "C" void kernel_launch(void* const* d_in, const int* in_sizes, int n_in,
                              void* d_out, int out_size, void* d_ws, size_t ws_size,
                              hipStream_t stream) {
  const float* emb = (const float*)d_in[0];
  const float* W_ii = (const float*)d_in[1];
  const float* b_ii = (const float*)d_in[2];
  const float* W_if = (const float*)d_in[3];
  const float* b_if = (const float*)d_in[4];
  const float* W_ig = (const float*)d_in[5];
  const float* b_ig = (const float*)d_in[6];
  const float* W_io = (const float*)d_in[7];
  const float* b_io = (const float*)d_in[8];
  const float* W_hi = (const float*)d_in[9];
  const float* W_hf = (const float*)d_in[10];
  const float* W_hg = (const float*)d_in[11];
  const float* W_ho = (const float*)d_in[12];

  char* ws = (char*)d_ws;
  uint16_t* embb  = (uint16_t*)ws;                       // 134217728 B (also hring)
  uint16_t* wx    = (uint16_t*)(ws + 134217728);         // 8388608 B
  uint16_t* wh    = (uint16_t*)(ws + 142606336);         // 8388608 B
  uint16_t* xp    = (uint16_t*)(ws + 150994944);         // 134217728 B (per-chunk)
  float*    cbuf  = (float*)(ws + 285212672);            // 262144 B
  uint32_t* flags = (uint32_t*)(ws + 285474816);         // 1048576 B

  hipMemsetAsync(flags, 0, (size_t)4 * NS * 64 * 4, stream);

  k_cvt<<<2048, 256, 0, stream>>>(emb, embb, 64 * 1024 * 1024 / 4);
  k_cvt<<<256, 256, 0, stream>>>(W_ii, wx + 0 * 1048576, 262144);
  k_cvt<<<256, 256, 0, stream>>>(W_if, wx + 1 * 1048576, 262144);
  k_cvt<<<256, 256, 0, stream>>>(W_ig, wx + 2 * 1048576, 262144);
  k_cvt<<<256, 256, 0, stream>>>(W_io, wx + 3 * 1048576, 262144);
  k_cvt<<<256, 256, 0, stream>>>(W_hi, wh + 0 * 1048576, 262144);
  k_cvt<<<256, 256, 0, stream>>>(W_hf, wh + 1 * 1048576, 262144);
  k_cvt<<<256, 256, 0, stream>>>(W_hg, wh + 2 * 1048576, 262144);
  k_cvt<<<256, 256, 0, stream>>>(W_ho, wh + 3 * 1048576, 262144);

  for (int chk = 0; chk < NCHUNK; ++chk) {
    k_gemm<<<dim3(128, 32), 256, 0, stream>>>(embb, wx, xp, chk * CHUNK);
    k_lstm<<<256, 256, 0, stream>>>(wh, xp, b_ii, b_if, b_ig, b_io,
                                    embb, cbuf, flags, (float*)d_out, chk * CHUNK);
  }
}

// Round 3
// 4921.427 us; speedup vs baseline: 1.4743x; 1.0652x over previous
//
#include <hip/hip_runtime.h>
#include <stdint.h>

#define NB 64
#define NS 1024
#define ND 1024
#define NG 4096
#define CHUNK 256
#define NCHUNK 4

typedef __attribute__((ext_vector_type(4))) float f32x4;
typedef __attribute__((ext_vector_type(8))) short bf16x8;

__device__ __forceinline__ float bf2f(uint16_t u) {
  return __uint_as_float(((uint32_t)u) << 16);
}
__device__ __forceinline__ uint16_t f2bf(float f) {
  uint32_t x = __float_as_uint(f);
  return (uint16_t)((x + 0x7fffu + ((x >> 16) & 1u)) >> 16);
}
__device__ __forceinline__ float sigmoidf_(float x) {
  x = fminf(fmaxf(x, -30.f), 30.f);
  return 1.f / (1.f + __expf(-x));
}
__device__ __forceinline__ float tanhf_(float x) {
  x = fminf(fmaxf(x, -15.f), 15.f);
  float e = __expf(2.f * x);
  return (e - 1.f) / (e + 1.f);
}
__device__ __forceinline__ void gload_lds16(const void* g, void* l) {
  __builtin_amdgcn_global_load_lds(
      (const __attribute__((address_space(1))) uint32_t*)g,
      (__attribute__((address_space(3))) uint32_t*)l, 16, 0, 0);
}

// ---------------- convert fp32 -> bf16 (weights only) ----------------
__global__ void k_cvt(const float* __restrict__ src, uint16_t* __restrict__ dst, int n4) {
  int stride = gridDim.x * blockDim.x;
  for (int i = blockIdx.x * blockDim.x + threadIdx.x; i < n4; i += stride) {
    float4 v = ((const float4*)src)[i];
    ushort4 o;
    o.x = f2bf(v.x); o.y = f2bf(v.y); o.z = f2bf(v.z); o.w = f2bf(v.w);
    ((ushort4*)dst)[i] = o;
  }
}

// ---------------- phase 1: x_proj chunk GEMM (A read fp32 + fused cvt) ----------------
__global__ __launch_bounds__(256) void k_gemm(const float* __restrict__ Af,
                                              const uint16_t* __restrict__ Wx,
                                              uint16_t* __restrict__ XP, int t0) {
  __shared__ uint16_t lA[128 * 32];
  __shared__ uint16_t lB[128 * 32];
  const int tid = threadIdx.x;
  const int mb = blockIdx.x, nb = blockIdx.y;
  const int b = mb >> 1;
  const int s_base = t0 + ((mb & 1) << 7);
  const float* A0 = Af + ((size_t)b * NS + s_base) * ND;
  const uint16_t* B0 = Wx + (size_t)(nb * 128) * ND;
  const int lane = tid & 63, wv = tid >> 6;
  const int m_off = (wv >> 1) << 6, n_off = (wv & 1) << 6;

  f32x4 acc[4][4] = {};
  for (int kb = 0; kb < ND / 32; ++kb) {
    const int k0 = kb * 32;
#pragma unroll
    for (int j = 0; j < 2; ++j) {
      int cid = j * 256 + tid;
      int row = cid >> 2, cc = cid & 3;
      int cs = cc ^ (row & 3);
      gload_lds16(B0 + (size_t)row * ND + k0 + cs * 8, (char*)lB + cid * 16);
    }
#pragma unroll
    for (int j = 0; j < 2; ++j) {
      int cid = j * 256 + tid;
      int row = cid >> 2, cc = cid & 3;
      const float* ap = A0 + (size_t)row * ND + k0 + cc * 8;
      float4 u = *(const float4*)ap;
      float4 w = *(const float4*)(ap + 4);
      bf16x8 pk;
      pk[0] = (short)f2bf(u.x); pk[1] = (short)f2bf(u.y);
      pk[2] = (short)f2bf(u.z); pk[3] = (short)f2bf(u.w);
      pk[4] = (short)f2bf(w.x); pk[5] = (short)f2bf(w.y);
      pk[6] = (short)f2bf(w.z); pk[7] = (short)f2bf(w.w);
      int cs = cc ^ (row & 3);
      *(bf16x8*)((char*)lA + row * 64 + cs * 16) = pk;
    }
    __syncthreads();
    bf16x8 af[4], bfr[4];
#pragma unroll
    for (int i = 0; i < 4; ++i) {
      int row = m_off + i * 16 + (lane & 15);
      int ch = (lane >> 4) ^ (row & 3);
      af[i] = *(const bf16x8*)((const char*)lA + row * 64 + ch * 16);
      int rowb = n_off + i * 16 + (lane & 15);
      int chb = (lane >> 4) ^ (rowb & 3);
      bfr[i] = *(const bf16x8*)((const char*)lB + rowb * 64 + chb * 16);
    }
#pragma unroll
    for (int i = 0; i < 4; ++i)
#pragma unroll
      for (int j2 = 0; j2 < 4; ++j2)
        acc[i][j2] = __builtin_amdgcn_mfma_f32_16x16x32_bf16(af[i], bfr[j2], acc[i][j2], 0, 0, 0);
    __syncthreads();
  }
  const int s_loc0 = ((mb & 1) << 7);
#pragma unroll
  for (int i = 0; i < 4; ++i)
#pragma unroll
    for (int j2 = 0; j2 < 4; ++j2)
#pragma unroll
      for (int r = 0; r < 4; ++r) {
        int m = m_off + i * 16 + ((lane >> 4) << 2) + r;
        int n = nb * 128 + n_off + j2 * 16 + (lane & 15);
        int s_loc = s_loc0 + m;
        XP[((size_t)(s_loc * NB + b)) * NG + n] = f2bf(acc[i][j2][r]);
      }
}

// ---------------- phase 2: persistent LSTM chunk ----------------
// 128 WGs x 512 threads: (g_b 0..3) x (g_d 0..31). WG owns 16 batches, 32 d.
// Wh in registers (128 VGPR/lane). h(t) published once into dedicated
// write-once hring[b][t][d] (fresh address per step -> plain cached consumer
// loads are correct by construction; producer stores are agent-scope so they
// reach L3 before the counter bump). One padded counter per (bg, t).
__global__ __launch_bounds__(512, 2) void k_lstm(
    const uint16_t* __restrict__ Wh,     // [4*1024][1024] bf16
    const uint16_t* __restrict__ XP,     // [CHUNK*64][4096] bf16 (chunk-local)
    const float* __restrict__ b_i, const float* __restrict__ b_f,
    const float* __restrict__ b_g, const float* __restrict__ b_o,
    uint16_t* __restrict__ hring,        // [NB][NS][ND] bf16, write-once
    float* __restrict__ cbuf,
    uint32_t* __restrict__ cnt,          // [NS][4] padded x32 dwords
    float* __restrict__ out, int t0) {
  __shared__ uint16_t lH[16 * 1024];     // 32 KB: 16 batch rows x 2048 B (swizzled)
  __shared__ uint16_t lHO[512];          // 1 KB h-pack buffer

  const int tid = threadIdx.x;
  const int lane = tid & 63, wv = tid >> 6;
  const int bid = blockIdx.x;
  const int xcd = bid & 7;
  const int g_b = xcd >> 1;                        // 2 XCDs per batch group
  const int g_d = (xcd & 1) + ((bid >> 3) << 1);   // 0..31

  const int q = lane >> 4, nl = lane & 15;
  const int g = nl & 3;                        // gate id
  const int d_loc = wv * 4 + (nl >> 2);        // 0..31
  const int dg = g_d * 32 + d_loc;             // global d
  const int bg0 = g_b * 16 + q * 4;            // batch base for r=0..3

  const uint16_t* wrow = Wh + ((size_t)g * ND + dg) * ND;
  bf16x8 wfr[32];
#pragma unroll
  for (int kk = 0; kk < 32; ++kk)
    wfr[kk] = *(const bf16x8*)(wrow + kk * 32 + q * 8);

  const float* bptr = (g == 0) ? b_i : (g == 1) ? b_f : (g == 2) ? b_g : b_o;
  const float Bv = bptr[dg];

  float c0, c1, c2, c3;
  if (t0 == 0) {
    c0 = c1 = c2 = c3 = 0.f;
  } else {
    c0 = cbuf[(size_t)(bg0 + 0) * ND + dg];
    c1 = cbuf[(size_t)(bg0 + 1) * ND + dg];
    c2 = cbuf[(size_t)(bg0 + 2) * ND + dg];
    c3 = cbuf[(size_t)(bg0 + 3) * ND + dg];
  }

#pragma unroll 1
  for (int t = t0; t < t0 + CHUNK; ++t) {
    // XP prefetch (independent of h)
    const uint16_t* xpb = XP + (((size_t)(t - t0) * NB) + bg0) * NG + ((size_t)g << 10) + dg;
    uint16_t x0 = xpb[0], x1 = xpb[NG], x2 = xpb[2 * (size_t)NG], x3 = xpb[3 * (size_t)NG];

    f32x4 a0 = {0,0,0,0}, a1 = {0,0,0,0}, a2 = {0,0,0,0}, a3 = {0,0,0,0};
    if (t > 0) {
      // single padded counter; wave-uniform poll (1 L3 transaction per poll)
      const uint32_t* cp = cnt + (((size_t)(t - 1) * 4) + g_b) * 32;
      uint32_t v;
      do {
        v = __hip_atomic_load(cp, __ATOMIC_RELAXED, __HIP_MEMORY_SCOPE_AGENT);
      } while (v < 32u);
      // stage h(t-1): 32 KB, plain cached global_load_lds, swizzle on source
#pragma unroll
      for (int j = 0; j < 4; ++j) {
        int ch = wv * 64 + j * 512 + lane;       // 0..2047
        int row = ch >> 7, c = ch & 127;
        const uint16_t* src = hring + ((size_t)(g_b * 16 + row) * NS + (t - 1)) * ND
                              + ((c ^ (row & 7)) << 3);
        gload_lds16(src, (char*)lH + ch * 16);
      }
      __syncthreads();
#pragma unroll
      for (int kk = 0; kk < 32; ++kk) {
        int cs = (kk * 4 + q) ^ (nl & 7);
        bf16x8 af = *(const bf16x8*)((const char*)lH + nl * 2048 + cs * 16);
        if ((kk & 3) == 0)      a0 = __builtin_amdgcn_mfma_f32_16x16x32_bf16(af, wfr[kk], a0, 0, 0, 0);
        else if ((kk & 3) == 1) a1 = __builtin_amdgcn_mfma_f32_16x16x32_bf16(af, wfr[kk], a1, 0, 0, 0);
        else if ((kk & 3) == 2) a2 = __builtin_amdgcn_mfma_f32_16x16x32_bf16(af, wfr[kk], a2, 0, 0, 0);
        else                    a3 = __builtin_amdgcn_mfma_f32_16x16x32_bf16(af, wfr[kk], a3, 0, 0, 0);
      }
    }

    float xr[4] = { bf2f(x0), bf2f(x1), bf2f(x2), bf2f(x3) };
    float cc[4] = { c0, c1, c2, c3 };
    float hval = 0.f;
#pragma unroll
    for (int r = 0; r < 4; ++r) {
      float v = a0[r] + a1[r] + a2[r] + a3[r] + xr[r] + Bv;
      float s1 = __shfl_xor(v, 1);
      float pe = (g & 1) ? s1 : v;
      float po = (g & 1) ? v : s1;
      float qe = __shfl_xor(pe, 2);
      float qo = __shfl_xor(po, 2);
      float gi = (g & 2) ? qe : pe;
      float gf = (g & 2) ? qo : po;
      float gg = (g & 2) ? pe : qe;
      float go = (g & 2) ? po : qo;
      float it = sigmoidf_(gi), ft = sigmoidf_(gf), gt = tanhf_(gg), ot = sigmoidf_(go);
      float cn = ft * cc[r] + it * gt;
      cc[r] = cn;
      float h = ot * tanhf_(cn);
      if (r == g) hval = h;
    }
    c0 = cc[0]; c1 = cc[1]; c2 = cc[2]; c3 = cc[3];

    lHO[(q * 4 + g) * 32 + d_loc] = f2bf(hval);
    if (t == NS - 1) out[(size_t)(bg0 + g) * ND + dg] = hval;
    __syncthreads();

    if (tid < 64) {
      int row = tid >> 2, seg = tid & 3;
      const uint64_t* s = (const uint64_t*)&lHO[row * 32 + seg * 8];
      uint64_t v0 = s[0], v1 = s[1];
      uint16_t* dst = hring + ((size_t)(g_b * 16 + row) * NS + t) * ND + g_d * 32 + seg * 8;
      __hip_atomic_store((uint64_t*)dst, v0, __ATOMIC_RELAXED, __HIP_MEMORY_SCOPE_AGENT);
      __hip_atomic_store((uint64_t*)(dst + 4), v1, __ATOMIC_RELAXED, __HIP_MEMORY_SCOPE_AGENT);
    }
    __syncthreads();   // drains h stores in wave 0 before the counter bump
    if (tid == 0)
      __hip_atomic_fetch_add((uint32_t*)(cnt + (((size_t)t * 4) + g_b) * 32), 1u,
                             __ATOMIC_RELAXED, __HIP_MEMORY_SCOPE_AGENT);
  }

  float cstore = (g == 0) ? c0 : (g == 1) ? c1 : (g == 2) ? c2 : c3;
  cbuf[(size_t)(bg0 + g) * ND + dg] = cstore;
}

// ---------------- launch ----------------
extern "C" void kernel_launch(void* const* d_in, const int* in_sizes, int n_in,
                              void* d_out, int out_size, void* d_ws, size_t ws_size,
                              hipStream_t stream) {
  const float* emb = (const float*)d_in[0];
  const float* W_ii = (const float*)d_in[1];
  const float* b_ii = (const float*)d_in[2];
  const float* W_if = (const float*)d_in[3];
  const float* b_if = (const float*)d_in[4];
  const float* W_ig = (const float*)d_in[5];
  const float* b_ig = (const float*)d_in[6];
  const float* W_io = (const float*)d_in[7];
  const float* b_io = (const float*)d_in[8];
  const float* W_hi = (const float*)d_in[9];
  const float* W_hf = (const float*)d_in[10];
  const float* W_hg = (const float*)d_in[11];
  const float* W_ho = (const float*)d_in[12];

  char* ws = (char*)d_ws;
  uint16_t* hring = (uint16_t*)ws;                       // 134217728 B [B][S][D] write-once
  uint16_t* wx    = (uint16_t*)(ws + 134217728);         // 8388608 B
  uint16_t* wh    = (uint16_t*)(ws + 142606336);         // 8388608 B
  uint16_t* xp    = (uint16_t*)(ws + 150994944);         // 134217728 B (per-chunk)
  float*    cbuf  = (float*)(ws + 285212672);            // 262144 B
  uint32_t* cnt   = (uint32_t*)(ws + 285474816);         // 524288 B [NS][4] x32 pad

  hipMemsetAsync(cnt, 0, (size_t)NS * 4 * 32 * 4, stream);

  k_cvt<<<256, 256, 0, stream>>>(W_ii, wx + 0 * 1048576, 262144);
  k_cvt<<<256, 256, 0, stream>>>(W_if, wx + 1 * 1048576, 262144);
  k_cvt<<<256, 256, 0, stream>>>(W_ig, wx + 2 * 1048576, 262144);
  k_cvt<<<256, 256, 0, stream>>>(W_io, wx + 3 * 1048576, 262144);
  k_cvt<<<256, 256, 0, stream>>>(W_hi, wh + 0 * 1048576, 262144);
  k_cvt<<<256, 256, 0, stream>>>(W_hf, wh + 1 * 1048576, 262144);
  k_cvt<<<256, 256, 0, stream>>>(W_hg, wh + 2 * 1048576, 262144);
  k_cvt<<<256, 256, 0, stream>>>(W_ho, wh + 3 * 1048576, 262144);

  for (int chk = 0; chk < NCHUNK; ++chk) {
    k_gemm<<<dim3(128, 32), 256, 0, stream>>>(emb, wx, xp, chk * CHUNK);
    k_lstm<<<128, 512, 0, stream>>>(wh, xp, b_ii, b_if, b_ig, b_io,
                                    hring, cbuf, cnt, (float*)d_out, chk * CHUNK);
  }
}

// Round 4
// 4906.133 us; speedup vs baseline: 1.4789x; 1.0031x over previous
//
#include <hip/hip_runtime.h>
#include <stdint.h>

#define NB 64
#define NS 1024
#define ND 1024
#define NG 4096
#define CHUNK 256
#define NCHUNK 4

typedef __attribute__((ext_vector_type(4))) float f32x4;
typedef __attribute__((ext_vector_type(8))) short bf16x8;

__device__ __forceinline__ float bf2f(uint16_t u) {
  return __uint_as_float(((uint32_t)u) << 16);
}
__device__ __forceinline__ uint16_t f2bf(float f) {
  uint32_t x = __float_as_uint(f);
  return (uint16_t)((x + 0x7fffu + ((x >> 16) & 1u)) >> 16);
}
// inf-safe, clamp-free
__device__ __forceinline__ float sigmoidf_(float x) {
  return 1.f / (1.f + __expf(-x));
}
__device__ __forceinline__ float tanhf_(float x) {
  return 1.f - 2.f / (__expf(x + x) + 1.f);
}
__device__ __forceinline__ void gload_lds16(const void* g, void* l) {
  __builtin_amdgcn_global_load_lds(
      (const __attribute__((address_space(1))) uint32_t*)g,
      (__attribute__((address_space(3))) uint32_t*)l, 16, 0, 0);
}

// ---------------- convert fp32 -> bf16 (weights only) ----------------
__global__ void k_cvt(const float* __restrict__ src, uint16_t* __restrict__ dst, int n4) {
  int stride = gridDim.x * blockDim.x;
  for (int i = blockIdx.x * blockDim.x + threadIdx.x; i < n4; i += stride) {
    float4 v = ((const float4*)src)[i];
    ushort4 o;
    o.x = f2bf(v.x); o.y = f2bf(v.y); o.z = f2bf(v.z); o.w = f2bf(v.w);
    ((ushort4*)dst)[i] = o;
  }
}

// ---------------- phase 1: x_proj chunk GEMM (A read fp32 + fused cvt) ----------------
__global__ __launch_bounds__(256) void k_gemm(const float* __restrict__ Af,
                                              const uint16_t* __restrict__ Wx,
                                              uint16_t* __restrict__ XP, int t0) {
  __shared__ uint16_t lA[128 * 32];
  __shared__ uint16_t lB[128 * 32];
  const int tid = threadIdx.x;
  const int mb = blockIdx.x, nb = blockIdx.y;
  const int b = mb >> 1;
  const int s_base = t0 + ((mb & 1) << 7);
  const float* A0 = Af + ((size_t)b * NS + s_base) * ND;
  const uint16_t* B0 = Wx + (size_t)(nb * 128) * ND;
  const int lane = tid & 63, wv = tid >> 6;
  const int m_off = (wv >> 1) << 6, n_off = (wv & 1) << 6;

  f32x4 acc[4][4] = {};
  for (int kb = 0; kb < ND / 32; ++kb) {
    const int k0 = kb * 32;
#pragma unroll
    for (int j = 0; j < 2; ++j) {
      int cid = j * 256 + tid;
      int row = cid >> 2, cc = cid & 3;
      int cs = cc ^ (row & 3);
      gload_lds16(B0 + (size_t)row * ND + k0 + cs * 8, (char*)lB + cid * 16);
    }
#pragma unroll
    for (int j = 0; j < 2; ++j) {
      int cid = j * 256 + tid;
      int row = cid >> 2, cc = cid & 3;
      const float* ap = A0 + (size_t)row * ND + k0 + cc * 8;
      float4 u = *(const float4*)ap;
      float4 w = *(const float4*)(ap + 4);
      bf16x8 pk;
      pk[0] = (short)f2bf(u.x); pk[1] = (short)f2bf(u.y);
      pk[2] = (short)f2bf(u.z); pk[3] = (short)f2bf(u.w);
      pk[4] = (short)f2bf(w.x); pk[5] = (short)f2bf(w.y);
      pk[6] = (short)f2bf(w.z); pk[7] = (short)f2bf(w.w);
      int cs = cc ^ (row & 3);
      *(bf16x8*)((char*)lA + row * 64 + cs * 16) = pk;
    }
    __syncthreads();
    bf16x8 af[4], bfr[4];
#pragma unroll
    for (int i = 0; i < 4; ++i) {
      int row = m_off + i * 16 + (lane & 15);
      int ch = (lane >> 4) ^ (row & 3);
      af[i] = *(const bf16x8*)((const char*)lA + row * 64 + ch * 16);
      int rowb = n_off + i * 16 + (lane & 15);
      int chb = (lane >> 4) ^ (rowb & 3);
      bfr[i] = *(const bf16x8*)((const char*)lB + rowb * 64 + chb * 16);
    }
#pragma unroll
    for (int i = 0; i < 4; ++i)
#pragma unroll
      for (int j2 = 0; j2 < 4; ++j2)
        acc[i][j2] = __builtin_amdgcn_mfma_f32_16x16x32_bf16(af[i], bfr[j2], acc[i][j2], 0, 0, 0);
    __syncthreads();
  }
  const int s_loc0 = ((mb & 1) << 7);
#pragma unroll
  for (int i = 0; i < 4; ++i)
#pragma unroll
    for (int j2 = 0; j2 < 4; ++j2)
#pragma unroll
      for (int r = 0; r < 4; ++r) {
        int m = m_off + i * 16 + ((lane >> 4) << 2) + r;
        int n = nb * 128 + n_off + j2 * 16 + (lane & 15);
        int s_loc = s_loc0 + m;
        XP[((size_t)(s_loc * NB + b)) * NG + n] = f2bf(acc[i][j2][r]);
      }
}

// ---------------- phase 2: persistent LSTM chunk ----------------
// 128 WGs x 512 threads: (g_b 0..3) x (g_d 0..31). WG owns 16 batches, 32 d.
// Wh in registers. h published per-wave (shuffle-packed 8B agent stores) into
// write-once hring[b][t][d]; one counter per (g_b,t); wave0-only L3 poll with
// LDS release flag for waves 1..7.
__global__ __launch_bounds__(512, 2) void k_lstm(
    const uint16_t* __restrict__ Wh,     // [4*1024][1024] bf16
    const uint16_t* __restrict__ XP,     // [CHUNK*64][4096] bf16 (chunk-local)
    const float* __restrict__ b_i, const float* __restrict__ b_f,
    const float* __restrict__ b_g, const float* __restrict__ b_o,
    uint16_t* __restrict__ hring,        // [NB][NS][ND] bf16, write-once
    float* __restrict__ cbuf,
    uint32_t* __restrict__ cnt,          // [NS][4] padded x32 dwords
    float* __restrict__ out, int t0) {
  __shared__ uint16_t lH[16 * 1024];     // 32 KB: 16 batch rows x 2048 B (swizzled)
  __shared__ int lds_sync;

  const int tid = threadIdx.x;
  const int lane = tid & 63, wv = tid >> 6;
  const int bid = blockIdx.x;
  const int xcd = bid & 7;
  const int g_b = xcd >> 1;                        // 2 XCDs per batch group
  const int g_d = (xcd & 1) + ((bid >> 3) << 1);   // 0..31

  const int q = lane >> 4, nl = lane & 15;
  const int g = nl & 3;                        // gate id (0=i,1=f,2=g,3=o)
  const int d_loc = wv * 4 + (nl >> 2);        // 0..31
  const int dg = g_d * 32 + d_loc;             // global d
  const int bg0 = g_b * 16 + q * 4;            // batch base for r=0..3

  const uint16_t* wrow = Wh + ((size_t)g * ND + dg) * ND;
  bf16x8 wfr[32];
#pragma unroll
  for (int kk = 0; kk < 32; ++kk)
    wfr[kk] = *(const bf16x8*)(wrow + kk * 32 + q * 8);

  const float* bptr = (g == 0) ? b_i : (g == 1) ? b_f : (g == 2) ? b_g : b_o;
  const float Bv = bptr[dg];

  float c0, c1, c2, c3;
  if (t0 == 0) {
    c0 = c1 = c2 = c3 = 0.f;
  } else {
    c0 = cbuf[(size_t)(bg0 + 0) * ND + dg];
    c1 = cbuf[(size_t)(bg0 + 1) * ND + dg];
    c2 = cbuf[(size_t)(bg0 + 2) * ND + dg];
    c3 = cbuf[(size_t)(bg0 + 3) * ND + dg];
  }

  if (tid == 0)
    __hip_atomic_store(&lds_sync, t0, __ATOMIC_RELAXED, __HIP_MEMORY_SCOPE_WORKGROUP);
  __syncthreads();

  // preload XP for t0
  const uint16_t* xp0 = XP + ((size_t)bg0) * NG + ((size_t)g << 10) + dg;
  uint16_t xc0 = xp0[0], xc1 = xp0[NG], xc2 = xp0[2 * (size_t)NG], xc3 = xp0[3 * (size_t)NG];

#pragma unroll 1
  for (int t = t0; t < t0 + CHUNK; ++t) {
    f32x4 a0 = {0,0,0,0}, a1 = {0,0,0,0}, a2 = {0,0,0,0}, a3 = {0,0,0,0};
    if (t > 0) {
      if (wv == 0) {
        const uint32_t* cp = cnt + (((size_t)(t - 1) * 4) + g_b) * 32;
        uint32_t v;
        do {
          v = __hip_atomic_load(cp, __ATOMIC_RELAXED, __HIP_MEMORY_SCOPE_AGENT);
        } while (v < 32u);
        if (lane == 0)
          __hip_atomic_store(&lds_sync, t, __ATOMIC_RELAXED, __HIP_MEMORY_SCOPE_WORKGROUP);
      } else {
        while (__hip_atomic_load(&lds_sync, __ATOMIC_RELAXED, __HIP_MEMORY_SCOPE_WORKGROUP) < t) {}
      }
      // stage h(t-1): 32 KB via global_load_lds, swizzle applied on source col
#pragma unroll
      for (int j = 0; j < 4; ++j) {
        int ch = wv * 64 + j * 512 + lane;       // 0..2047
        int row = ch >> 7, c = ch & 127;
        const uint16_t* src = hring + ((size_t)(g_b * 16 + row) * NS + (t - 1)) * ND
                              + ((c ^ (row & 7)) << 3);
        gload_lds16(src, (char*)lH + ch * 16);
      }
      __syncthreads();
    }

    // prefetch next step's XP into regs (covered by MFMA+VALU below)
    int tn = t + 1 < t0 + CHUNK ? t + 1 : t;
    const uint16_t* xpn = XP + (((size_t)(tn - t0) * NB) + bg0) * NG + ((size_t)g << 10) + dg;
    uint16_t xn0 = xpn[0], xn1 = xpn[NG], xn2 = xpn[2 * (size_t)NG], xn3 = xpn[3 * (size_t)NG];

    if (t > 0) {
#pragma unroll
      for (int kk = 0; kk < 32; ++kk) {
        int cs = (kk * 4 + q) ^ (nl & 7);
        bf16x8 af = *(const bf16x8*)((const char*)lH + nl * 2048 + cs * 16);
        if ((kk & 3) == 0)      a0 = __builtin_amdgcn_mfma_f32_16x16x32_bf16(af, wfr[kk], a0, 0, 0, 0);
        else if ((kk & 3) == 1) a1 = __builtin_amdgcn_mfma_f32_16x16x32_bf16(af, wfr[kk], a1, 0, 0, 0);
        else if ((kk & 3) == 2) a2 = __builtin_amdgcn_mfma_f32_16x16x32_bf16(af, wfr[kk], a2, 0, 0, 0);
        else                    a3 = __builtin_amdgcn_mfma_f32_16x16x32_bf16(af, wfr[kk], a3, 0, 0, 0);
      }
    }

    float xr[4] = { bf2f(xc0), bf2f(xc1), bf2f(xc2), bf2f(xc3) };
    float cc[4] = { c0, c1, c2, c3 };
    float hval = 0.f;
#pragma unroll
    for (int r = 0; r < 4; ++r) {
      float v = a0[r] + a1[r] + a2[r] + a3[r] + xr[r] + Bv;
      // activate OWN gate first (1 transcendental), then butterfly-allgather
      float act = (g == 2) ? tanhf_(v) : sigmoidf_(v);
      float s1 = __shfl_xor(act, 1);
      float pe = (g & 1) ? s1 : act;
      float po = (g & 1) ? act : s1;
      float qe = __shfl_xor(pe, 2);
      float qo = __shfl_xor(po, 2);
      float gi = (g & 2) ? qe : pe;
      float gf = (g & 2) ? qo : po;
      float gg = (g & 2) ? pe : qe;
      float go = (g & 2) ? po : qo;
      float cn = __builtin_fmaf(gf, cc[r], gi * gg);
      cc[r] = cn;
      float h = go * tanhf_(cn);
      if (r == g) hval = h;
    }
    c0 = cc[0]; c1 = cc[1]; c2 = cc[2]; c3 = cc[3];

    // per-wave shuffle-pack: 4 lanes (same q,g-row, d_off 0..3) -> u64 in nl<4
    {
      int hv = (int)f2bf(hval);
      int p = __shfl_xor(hv, 4);
      uint32_t v32 = ((nl >> 2) & 1) ? ((uint32_t)p | ((uint32_t)hv << 16))
                                     : ((uint32_t)hv | ((uint32_t)p << 16));
      uint32_t hi = (uint32_t)__shfl_xor((int)v32, 8);
      if (nl < 4) {
        uint64_t val = (uint64_t)v32 | ((uint64_t)hi << 32);
        uint16_t* dst = hring + ((size_t)(g_b * 16 + q * 4 + nl) * NS + t) * ND
                        + g_d * 32 + wv * 4;
        __hip_atomic_store((uint64_t*)dst, val, __ATOMIC_RELAXED, __HIP_MEMORY_SCOPE_AGENT);
      }
    }
    if (t == NS - 1) out[(size_t)(bg0 + g) * ND + dg] = hval;

    __syncthreads();   // each wave drains its h stores before barrier; guards lH reuse
    if (tid == 0)
      __hip_atomic_fetch_add((uint32_t*)(cnt + (((size_t)t * 4) + g_b) * 32), 1u,
                             __ATOMIC_RELAXED, __HIP_MEMORY_SCOPE_AGENT);

    xc0 = xn0; xc1 = xn1; xc2 = xn2; xc3 = xn3;
  }

  float cstore = (g == 0) ? c0 : (g == 1) ? c1 : (g == 2) ? c2 : c3;
  cbuf[(size_t)(bg0 + g) * ND + dg] = cstore;
}

// ---------------- launch ----------------
extern "C" void kernel_launch(void* const* d_in, const int* in_sizes, int n_in,
                              void* d_out, int out_size, void* d_ws, size_t ws_size,
                              hipStream_t stream) {
  const float* emb = (const float*)d_in[0];
  const float* W_ii = (const float*)d_in[1];
  const float* b_ii = (const float*)d_in[2];
  const float* W_if = (const float*)d_in[3];
  const float* b_if = (const float*)d_in[4];
  const float* W_ig = (const float*)d_in[5];
  const float* b_ig = (const float*)d_in[6];
  const float* W_io = (const float*)d_in[7];
  const float* b_io = (const float*)d_in[8];
  const float* W_hi = (const float*)d_in[9];
  const float* W_hf = (const float*)d_in[10];
  const float* W_hg = (const float*)d_in[11];
  const float* W_ho = (const float*)d_in[12];

  char* ws = (char*)d_ws;
  uint16_t* hring = (uint16_t*)ws;                       // 134217728 B [B][S][D] write-once
  uint16_t* wx    = (uint16_t*)(ws + 134217728);         // 8388608 B
  uint16_t* wh    = (uint16_t*)(ws + 142606336);         // 8388608 B
  uint16_t* xp    = (uint16_t*)(ws + 150994944);         // 134217728 B (per-chunk)
  float*    cbuf  = (float*)(ws + 285212672);            // 262144 B
  uint32_t* cnt   = (uint32_t*)(ws + 285474816);         // 524288 B [NS][4] x32 pad

  hipMemsetAsync(cnt, 0, (size_t)NS * 4 * 32 * 4, stream);

  k_cvt<<<256, 256, 0, stream>>>(W_ii, wx + 0 * 1048576, 262144);
  k_cvt<<<256, 256, 0, stream>>>(W_if, wx + 1 * 1048576, 262144);
  k_cvt<<<256, 256, 0, stream>>>(W_ig, wx + 2 * 1048576, 262144);
  k_cvt<<<256, 256, 0, stream>>>(W_io, wx + 3 * 1048576, 262144);
  k_cvt<<<256, 256, 0, stream>>>(W_hi, wh + 0 * 1048576, 262144);
  k_cvt<<<256, 256, 0, stream>>>(W_hf, wh + 1 * 1048576, 262144);
  k_cvt<<<256, 256, 0, stream>>>(W_hg, wh + 2 * 1048576, 262144);
  k_cvt<<<256, 256, 0, stream>>>(W_ho, wh + 3 * 1048576, 262144);

  for (int chk = 0; chk < NCHUNK; ++chk) {
    k_gemm<<<dim3(128, 32), 256, 0, stream>>>(emb, wx, xp, chk * CHUNK);
    k_lstm<<<128, 512, 0, stream>>>(wh, xp, b_ii, b_if, b_ig, b_io,
                                    hring, cbuf, cnt, (float*)d_out, chk * CHUNK);
  }
}

// Round 5
// 4582.261 us; speedup vs baseline: 1.5835x; 1.0707x over previous
//
#include <hip/hip_runtime.h>
#include <stdint.h>

#define NB 64
#define NS 1024
#define ND 1024
#define NG 4096
#define CHUNK 128
#define NCHUNK 8

typedef __attribute__((ext_vector_type(4))) float f32x4;
typedef __attribute__((ext_vector_type(8))) short bf16x8;

__device__ __forceinline__ float bf2f(uint16_t u) {
  return __uint_as_float(((uint32_t)u) << 16);
}
__device__ __forceinline__ uint16_t f2bf(float f) {
  uint32_t x = __float_as_uint(f);
  return (uint16_t)((x + 0x7fffu + ((x >> 16) & 1u)) >> 16);
}
// inf-safe, clamp-free
__device__ __forceinline__ float sigmoidf_(float x) {
  return 1.f / (1.f + __expf(-x));
}
__device__ __forceinline__ float tanhf_(float x) {
  return 1.f - 2.f / (__expf(x + x) + 1.f);
}
__device__ __forceinline__ void gload_lds16(const void* g, void* l) {
  __builtin_amdgcn_global_load_lds(
      (const __attribute__((address_space(1))) uint32_t*)g,
      (__attribute__((address_space(3))) uint32_t*)l, 16, 0, 0);
}

// ---------------- convert fp32 -> bf16 (weights only) ----------------
__global__ void k_cvt(const float* __restrict__ src, uint16_t* __restrict__ dst, int n4) {
  int stride = gridDim.x * blockDim.x;
  for (int i = blockIdx.x * blockDim.x + threadIdx.x; i < n4; i += stride) {
    float4 v = ((const float4*)src)[i];
    ushort4 o;
    o.x = f2bf(v.x); o.y = f2bf(v.y); o.z = f2bf(v.z); o.w = f2bf(v.w);
    ((ushort4*)dst)[i] = o;
  }
}

// ---------------- GEMM tile: [128 steps x 1024] x [1024 x 128] -> XP ----------------
// tid in 0..255 (one 256-thread worker), lmem = 16 KB scratch.
__device__ __forceinline__ void gemm_tile(const float* __restrict__ A0,
                                          const uint16_t* __restrict__ Wx,
                                          uint16_t* __restrict__ XP,
                                          int b, int nb, int tid, char* lmem) {
  uint16_t* lAx = (uint16_t*)lmem;           // [128][32] bf16 (swizzled 16B chunks)
  uint16_t* lBx = (uint16_t*)(lmem + 8192);  // [128][32]
  const uint16_t* B0 = Wx + (size_t)(nb * 128) * ND;
  const int lane = tid & 63, wv = tid >> 6;  // wv 0..3
  const int m_off = (wv >> 1) << 6, n_off = (wv & 1) << 6;

  f32x4 acc[4][4] = {};
  for (int kb = 0; kb < ND / 32; ++kb) {
    const int k0 = kb * 32;
#pragma unroll
    for (int j = 0; j < 2; ++j) {
      int cid = j * 256 + tid;
      int row = cid >> 2, cc = cid & 3;
      int cs = cc ^ (row & 3);
      gload_lds16(B0 + (size_t)row * ND + k0 + cs * 8, (char*)lBx + cid * 16);
    }
#pragma unroll
    for (int j = 0; j < 2; ++j) {
      int cid = j * 256 + tid;
      int row = cid >> 2, cc = cid & 3;
      const float* ap = A0 + (size_t)row * ND + k0 + cc * 8;
      float4 u = *(const float4*)ap;
      float4 w = *(const float4*)(ap + 4);
      bf16x8 pk;
      pk[0] = (short)f2bf(u.x); pk[1] = (short)f2bf(u.y);
      pk[2] = (short)f2bf(u.z); pk[3] = (short)f2bf(u.w);
      pk[4] = (short)f2bf(w.x); pk[5] = (short)f2bf(w.y);
      pk[6] = (short)f2bf(w.z); pk[7] = (short)f2bf(w.w);
      int cs = cc ^ (row & 3);
      *(bf16x8*)((char*)lAx + row * 64 + cs * 16) = pk;
    }
    __syncthreads();
    bf16x8 af[4], bfr[4];
#pragma unroll
    for (int i = 0; i < 4; ++i) {
      int row = m_off + i * 16 + (lane & 15);
      int ch = (lane >> 4) ^ (row & 3);
      af[i] = *(const bf16x8*)((const char*)lAx + row * 64 + ch * 16);
      int rowb = n_off + i * 16 + (lane & 15);
      int chb = (lane >> 4) ^ (rowb & 3);
      bfr[i] = *(const bf16x8*)((const char*)lBx + rowb * 64 + chb * 16);
    }
#pragma unroll
    for (int i = 0; i < 4; ++i)
#pragma unroll
      for (int j2 = 0; j2 < 4; ++j2)
        acc[i][j2] = __builtin_amdgcn_mfma_f32_16x16x32_bf16(af[i], bfr[j2], acc[i][j2], 0, 0, 0);
    __syncthreads();
  }
#pragma unroll
  for (int i = 0; i < 4; ++i)
#pragma unroll
    for (int j2 = 0; j2 < 4; ++j2)
#pragma unroll
      for (int r = 0; r < 4; ++r) {
        int m = m_off + i * 16 + ((lane >> 4) << 2) + r;       // s offset 0..127
        int n = nb * 128 + n_off + j2 * 16 + (lane & 15);
        XP[((size_t)(m * NB + b)) * NG + n] = f2bf(acc[i][j2][r]);
      }
}

// ---------------- fused dispatch: lstm(chunk) on bids 0..127, gemm(chunk+1) on 128..255 ----
// lstm: (g_b 0..3) x (g_d 0..31); WG owns 16 batches x 32 d; Wh in registers.
// Sync: producers plain-store per-WG flags (16B-strided slots, no RMW);
// consumer wave0 gathers 32 flags in one 32-lane load, releases via LDS.
__global__ __launch_bounds__(512, 2) void k_fused(
    const float* __restrict__ emb,       // [64][1024][1024] fp32
    const uint16_t* __restrict__ Wx,     // [4096][1024] bf16
    const uint16_t* __restrict__ Wh,     // [4096][1024] bf16
    uint16_t* __restrict__ xpA, uint16_t* __restrict__ xpB,   // [128][64][4096] bf16
    const float* __restrict__ b_i, const float* __restrict__ b_f,
    const float* __restrict__ b_g, const float* __restrict__ b_o,
    uint16_t* __restrict__ hring,        // [NB][NS][ND] bf16, write-once
    float* __restrict__ cbuf,
    uint32_t* __restrict__ flags,        // [NS][4][32] slots, 16B stride
    float* __restrict__ out, int chunk) {
  __shared__ char smem[33024];           // lstm: 32KB lH + sync; gemm: 2 x 16KB
  const int bid = blockIdx.x;
  const int tid = threadIdx.x;

  if (bid >= 128) {
    // ---------------- GEMM role: x_proj for chunk+1 ----------------
    const int gc = chunk + 1;
    if (gc >= NCHUNK) return;
    uint16_t* XP = (gc & 1) ? xpB : xpA;
    const int worker = ((bid - 128) << 1) | (tid >> 8);   // 0..255
    const int t256 = tid & 255;
    char* lmem = smem + ((tid >> 8) << 14);
    const int t0 = gc * CHUNK;
    for (int job = worker; job < 64 * 32; job += 256) {
      int b = job & 63, nb = job >> 6;
      gemm_tile(emb + ((size_t)b * NS + t0) * ND, Wx, XP, b, nb, t256, lmem);
    }
    return;
  }
  if (chunk < 0) return;

  // ---------------- LSTM role ----------------
  uint16_t* lH = (uint16_t*)smem;                 // 32 KB: 16 rows x 2048 B
  int* lds_sync = (int*)(smem + 32768);
  const int t0 = chunk * CHUNK;
  const uint16_t* XP = (chunk & 1) ? xpB : xpA;

  const int lane = tid & 63, wv = tid >> 6;
  const int xcd = bid & 7;
  const int g_b = xcd >> 1;
  const int g_d = (xcd & 1) + ((bid >> 3) << 1);  // 0..31

  const int q = lane >> 4, nl = lane & 15;
  const int g = nl & 3;                        // gate id (0=i,1=f,2=g,3=o)
  const int d_loc = wv * 4 + (nl >> 2);        // 0..31
  const int dg = g_d * 32 + d_loc;             // global d
  const int bg0 = g_b * 16 + q * 4;            // batch base for r=0..3

  const uint16_t* wrow = Wh + ((size_t)g * ND + dg) * ND;
  bf16x8 wfr[32];
#pragma unroll
  for (int kk = 0; kk < 32; ++kk)
    wfr[kk] = *(const bf16x8*)(wrow + kk * 32 + q * 8);

  const float* bptr = (g == 0) ? b_i : (g == 1) ? b_f : (g == 2) ? b_g : b_o;
  const float Bv = bptr[dg];

  float c0, c1, c2, c3;
  if (t0 == 0) {
    c0 = c1 = c2 = c3 = 0.f;
  } else {
    c0 = cbuf[(size_t)(bg0 + 0) * ND + dg];
    c1 = cbuf[(size_t)(bg0 + 1) * ND + dg];
    c2 = cbuf[(size_t)(bg0 + 2) * ND + dg];
    c3 = cbuf[(size_t)(bg0 + 3) * ND + dg];
  }

  if (tid == 0)
    __hip_atomic_store(lds_sync, t0, __ATOMIC_RELAXED, __HIP_MEMORY_SCOPE_WORKGROUP);
  __syncthreads();

  // preload XP for t0
  const uint16_t* xp0 = XP + ((size_t)bg0) * NG + ((size_t)g << 10) + dg;
  uint16_t xc0 = xp0[0], xc1 = xp0[NG], xc2 = xp0[2 * (size_t)NG], xc3 = xp0[3 * (size_t)NG];

#pragma unroll 1
  for (int t = t0; t < t0 + CHUNK; ++t) {
    f32x4 a0 = {0,0,0,0}, a1 = {0,0,0,0}, a2 = {0,0,0,0}, a3 = {0,0,0,0};
    if (t > 0) {
      if (wv == 0) {
        // gather all 32 producer flags in one 32-lane load (slots 16B-strided)
        const uint32_t* fl = flags + ((((size_t)(t - 1) * 4 + g_b) << 5) + (lane & 31)) * 4;
        uint32_t v;
        do {
          v = __hip_atomic_load(fl, __ATOMIC_RELAXED, __HIP_MEMORY_SCOPE_AGENT);
        } while (__any(v == 0));
        if (lane == 0)
          __hip_atomic_store(lds_sync, t, __ATOMIC_RELAXED, __HIP_MEMORY_SCOPE_WORKGROUP);
      } else {
        while (__hip_atomic_load(lds_sync, __ATOMIC_RELAXED, __HIP_MEMORY_SCOPE_WORKGROUP) < t) {}
      }
      // stage h(t-1): 32 KB via global_load_lds, swizzle applied on source col
#pragma unroll
      for (int j = 0; j < 4; ++j) {
        int ch = wv * 64 + j * 512 + lane;       // 0..2047
        int row = ch >> 7, c = ch & 127;
        const uint16_t* src = hring + ((size_t)(g_b * 16 + row) * NS + (t - 1)) * ND
                              + ((c ^ (row & 7)) << 3);
        gload_lds16(src, (char*)lH + ch * 16);
      }
      __syncthreads();
    }

    // prefetch next step's XP into regs (covered by MFMA+VALU below)
    int tn = t + 1 < t0 + CHUNK ? t + 1 : t;
    const uint16_t* xpn = XP + (((size_t)(tn - t0) * NB) + bg0) * NG + ((size_t)g << 10) + dg;
    uint16_t xn0 = xpn[0], xn1 = xpn[NG], xn2 = xpn[2 * (size_t)NG], xn3 = xpn[3 * (size_t)NG];

    if (t > 0) {
#pragma unroll
      for (int kk = 0; kk < 32; ++kk) {
        int cs = (kk * 4 + q) ^ (nl & 7);
        bf16x8 af = *(const bf16x8*)((const char*)lH + nl * 2048 + cs * 16);
        if ((kk & 3) == 0)      a0 = __builtin_amdgcn_mfma_f32_16x16x32_bf16(af, wfr[kk], a0, 0, 0, 0);
        else if ((kk & 3) == 1) a1 = __builtin_amdgcn_mfma_f32_16x16x32_bf16(af, wfr[kk], a1, 0, 0, 0);
        else if ((kk & 3) == 2) a2 = __builtin_amdgcn_mfma_f32_16x16x32_bf16(af, wfr[kk], a2, 0, 0, 0);
        else                    a3 = __builtin_amdgcn_mfma_f32_16x16x32_bf16(af, wfr[kk], a3, 0, 0, 0);
      }
    }

    float xr[4] = { bf2f(xc0), bf2f(xc1), bf2f(xc2), bf2f(xc3) };
    float cc[4] = { c0, c1, c2, c3 };
    float hval = 0.f;
#pragma unroll
    for (int r = 0; r < 4; ++r) {
      float v = a0[r] + a1[r] + a2[r] + a3[r] + xr[r] + Bv;
      // activate OWN gate first (1 transcendental), then butterfly-allgather
      float act = (g == 2) ? tanhf_(v) : sigmoidf_(v);
      float s1 = __shfl_xor(act, 1);
      float pe = (g & 1) ? s1 : act;
      float po = (g & 1) ? act : s1;
      float qe = __shfl_xor(pe, 2);
      float qo = __shfl_xor(po, 2);
      float gi = (g & 2) ? qe : pe;
      float gf = (g & 2) ? qo : po;
      float gg = (g & 2) ? pe : qe;
      float go = (g & 2) ? po : qo;
      float cn = __builtin_fmaf(gf, cc[r], gi * gg);
      cc[r] = cn;
      float h = go * tanhf_(cn);
      if (r == g) hval = h;
    }
    c0 = cc[0]; c1 = cc[1]; c2 = cc[2]; c3 = cc[3];

    // per-wave shuffle-pack: 4 lanes (same q, d_off 0..3) -> u64 in nl<4
    {
      int hv = (int)f2bf(hval);
      int p = __shfl_xor(hv, 4);
      uint32_t v32 = ((nl >> 2) & 1) ? ((uint32_t)p | ((uint32_t)hv << 16))
                                     : ((uint32_t)hv | ((uint32_t)p << 16));
      uint32_t hi = (uint32_t)__shfl_xor((int)v32, 8);
      if (nl < 4) {
        uint64_t val = (uint64_t)v32 | ((uint64_t)hi << 32);
        uint16_t* dst = hring + ((size_t)(g_b * 16 + q * 4 + nl) * NS + t) * ND
                        + g_d * 32 + wv * 4;
        __hip_atomic_store((uint64_t*)dst, val, __ATOMIC_RELAXED, __HIP_MEMORY_SCOPE_AGENT);
      }
    }
    if (t == NS - 1) out[(size_t)(bg0 + g) * ND + dg] = hval;

    __syncthreads();   // each wave drains its h stores before barrier; guards lH reuse
    if (tid == 0)
      __hip_atomic_store(flags + ((((size_t)t * 4 + g_b) << 5) + g_d) * 4, 1u,
                         __ATOMIC_RELAXED, __HIP_MEMORY_SCOPE_AGENT);

    xc0 = xn0; xc1 = xn1; xc2 = xn2; xc3 = xn3;
  }

  float cstore = (g == 0) ? c0 : (g == 1) ? c1 : (g == 2) ? c2 : c3;
  cbuf[(size_t)(bg0 + g) * ND + dg] = cstore;
}

// ---------------- launch ----------------
extern "C" void kernel_launch(void* const* d_in, const int* in_sizes, int n_in,
                              void* d_out, int out_size, void* d_ws, size_t ws_size,
                              hipStream_t stream) {
  const float* emb = (const float*)d_in[0];
  const float* W_ii = (const float*)d_in[1];
  const float* b_ii = (const float*)d_in[2];
  const float* W_if = (const float*)d_in[3];
  const float* b_if = (const float*)d_in[4];
  const float* W_ig = (const float*)d_in[5];
  const float* b_ig = (const float*)d_in[6];
  const float* W_io = (const float*)d_in[7];
  const float* b_io = (const float*)d_in[8];
  const float* W_hi = (const float*)d_in[9];
  const float* W_hf = (const float*)d_in[10];
  const float* W_hg = (const float*)d_in[11];
  const float* W_ho = (const float*)d_in[12];

  char* ws = (char*)d_ws;
  uint16_t* hring = (uint16_t*)ws;                       // 134217728 B [B][S][D]
  uint16_t* wx    = (uint16_t*)(ws + 134217728);         // 8388608 B
  uint16_t* wh    = (uint16_t*)(ws + 142606336);         // 8388608 B
  uint16_t* xpA   = (uint16_t*)(ws + 150994944);         // 67108864 B
  uint16_t* xpB   = (uint16_t*)(ws + 218103808);         // 67108864 B
  float*    cbuf  = (float*)(ws + 285212672);            // 262144 B
  uint32_t* flags = (uint32_t*)(ws + 285474816);         // 2097152 B [NS][4][32] x16B

  hipMemsetAsync(flags, 0, 2097152, stream);

  k_cvt<<<256, 256, 0, stream>>>(W_ii, wx + 0 * 1048576, 262144);
  k_cvt<<<256, 256, 0, stream>>>(W_if, wx + 1 * 1048576, 262144);
  k_cvt<<<256, 256, 0, stream>>>(W_ig, wx + 2 * 1048576, 262144);
  k_cvt<<<256, 256, 0, stream>>>(W_io, wx + 3 * 1048576, 262144);
  k_cvt<<<256, 256, 0, stream>>>(W_hi, wh + 0 * 1048576, 262144);
  k_cvt<<<256, 256, 0, stream>>>(W_hf, wh + 1 * 1048576, 262144);
  k_cvt<<<256, 256, 0, stream>>>(W_hg, wh + 2 * 1048576, 262144);
  k_cvt<<<256, 256, 0, stream>>>(W_ho, wh + 3 * 1048576, 262144);

  // prologue: gemm for chunk 0 only (lstm WGs exit)
  k_fused<<<256, 512, 0, stream>>>(emb, wx, wh, xpA, xpB, b_ii, b_if, b_ig, b_io,
                                   hring, cbuf, flags, (float*)d_out, -1);
  for (int chk = 0; chk < NCHUNK; ++chk)
    k_fused<<<256, 512, 0, stream>>>(emb, wx, wh, xpA, xpB, b_ii, b_if, b_ig, b_io,
                                     hring, cbuf, flags, (float*)d_out, chk);
}